// Round 11
// baseline (570.490 us; speedup 1.0000x reference)
//
#include <hip/hip_runtime.h>
#include <hip/hip_bf16.h>

#define SEQ   2048
#define BATCH 256
#define HDIM  64
#define GDIM  256   // 4*H

typedef __attribute__((ext_vector_type(8))) short bf16x8;  // 8 bf16 = 4 VGPR
typedef __attribute__((ext_vector_type(4))) float f32x4;

static __device__ __forceinline__ unsigned short f2bf(float f) {
    return __builtin_bit_cast(unsigned short, __float2bfloat16(f));
}

// MFMA LSTM. One WG per batch element, 4 waves; wave w owns units [16w,16w+16).
// r9 skeleton (proven through graph-replay validation) with ONE change:
// the two K-halves per gate are now 8 INDEPENDENT mfma_16x16x32_bf16
// (Ca = bias, Cb = 0), combined post-hoc with VALU adds -> one MFMA latency
// level on the serial chain instead of two.
// h fed back as plain bf16 via LDS; x@Wih on VALU in fp32; saturating tanh.
// D layout (validated r8): col=lane&15, rows replicated -> lane reads acc[0].
// Barrier = raw lgkmcnt(0)+s_barrier (global stores stay in flight).
__global__ __launch_bounds__(256, 1) void lstm_mfma4(
    const float* __restrict__ xin,   // [S,B,2]
    const float* __restrict__ Wih,   // [2,256]
    const float* __restrict__ Whh,   // [64,256]
    const float* __restrict__ bih,   // [256]
    const float* __restrict__ bhh,   // [256]
    float* __restrict__ out)         // fp32: hidden_seq [S,B,64] | h [B,64] | c [B,64]
{
    const int b   = blockIdx.x;
    const int tid = threadIdx.x;
    const int w   = tid >> 6;    // wave 0..3
    const int l   = tid & 63;    // lane
    const int lg  = l >> 4;      // k-group 0..3
    const int lc  = l & 15;      // tile column
    const int u   = 16 * w + lc; // hidden unit this lane handles

    __shared__ __align__(16) unsigned short v_hi[2][HDIM];  // h bf16, dbuf
    __shared__ float2 xf[SEQ];                              // staged x pairs (fp32)

    // ---- stage x for this batch column ----
    const float2* x2 = reinterpret_cast<const float2*>(xin);
    #pragma unroll
    for (int r = 0; r < SEQ / 256; ++r) {
        int s = r * 256 + tid;
        xf[s] = x2[(size_t)s * BATCH + b];
    }

    // ---- persistent weight fragments (B operand): gate g = 64t + 16w + lc,
    //      k = 32*kc + 8*lg + e ----
    bf16x8 wf[4][2];
    f32x4  biasv[4];
    float  wx0[4], wx1[4];
    #pragma unroll
    for (int t = 0; t < 4; ++t) {
        const int g = 64 * t + 16 * w + lc;
        #pragma unroll
        for (int kc = 0; kc < 2; ++kc) {
            bf16x8 f;
            #pragma unroll
            for (int e = 0; e < 8; ++e) {
                int k = 32 * kc + 8 * lg + e;
                f[e] = (short)f2bf(Whh[k * GDIM + g]);
            }
            wf[t][kc] = f;
        }
        wx0[t] = Wih[0 * GDIM + g];
        wx1[t] = Wih[1 * GDIM + g];
        const float bb = bih[g] + bhh[g];
        biasv[t] = (f32x4){bb, bb, bb, bb};
    }

    if (tid < HDIM) { v_hi[0][tid] = 0; v_hi[1][tid] = 0; }
    float c_state = 0.0f, hval = 0.0f;
    __syncthreads();

    const float L2E = 1.44269504088896340736f;
    const f32x4 zeroC = {0.0f, 0.0f, 0.0f, 0.0f};

    for (int s = 0; s < SEQ; ++s) {
        const int buf = s & 1;
        // A fragments: h vector, identical across the 16 replica rows
        bf16x8 ah0 = *reinterpret_cast<const bf16x8*>(&v_hi[buf][8 * lg]);       // k 0..31
        bf16x8 ah1 = *reinterpret_cast<const bf16x8*>(&v_hi[buf][32 + 8 * lg]);  // k 32..63

        // x contribution in fp32 on VALU (overlaps the ds_reads)
        const float2 xv = xf[s];
        float xb[4];
        #pragma unroll
        for (int t = 0; t < 4; ++t)
            xb[t] = wx0[t] * xv.x + wx1[t] * xv.y;

        // 8 independent MFMAs: two K-halves per gate (bias in Ca, zero Cb)
        f32x4 aa[4], ab[4];
        #pragma unroll
        for (int t = 0; t < 4; ++t)
            aa[t] = __builtin_amdgcn_mfma_f32_16x16x32_bf16(ah0, wf[t][0], biasv[t], 0, 0, 0);
        #pragma unroll
        for (int t = 0; t < 4; ++t)
            ab[t] = __builtin_amdgcn_mfma_f32_16x16x32_bf16(ah1, wf[t][1], zeroC, 0, 0, 0);

        const float ip = (aa[0][0] + ab[0][0]) + xb[0];
        const float fp = (aa[1][0] + ab[1][0]) + xb[1];
        const float gp = (aa[2][0] + ab[2][0]) + xb[2];
        const float op = (aa[3][0] + ab[3][0]) + xb[3];

        // activations (in-lane): i,f,o sigmoid; g tanh (saturating forms)
        const float iv = __builtin_amdgcn_rcpf(1.0f + __builtin_amdgcn_exp2f(-L2E * ip));
        const float fv = __builtin_amdgcn_rcpf(1.0f + __builtin_amdgcn_exp2f(-L2E * fp));
        const float gv = 2.0f * __builtin_amdgcn_rcpf(1.0f + __builtin_amdgcn_exp2f(-2.0f * L2E * gp)) - 1.0f;
        const float ov = __builtin_amdgcn_rcpf(1.0f + __builtin_amdgcn_exp2f(-L2E * op));

        c_state = fv * c_state + iv * gv;
        const float tc = 2.0f * __builtin_amdgcn_rcpf(1.0f + __builtin_amdgcn_exp2f(-2.0f * L2E * c_state)) - 1.0f;
        hval = ov * tc;

        if (l < 16) {
            v_hi[buf ^ 1][u] = f2bf(hval);   // feed next step (bf16)
            out[(size_t)s * (BATCH * HDIM) + (size_t)b * HDIM + u] = hval;  // fire-and-forget
        }

        // LDS-only barrier: order h exchange WITHOUT draining global stores
        __builtin_amdgcn_sched_barrier(0);
        asm volatile("s_waitcnt lgkmcnt(0)\n\ts_barrier" ::: "memory");
        __builtin_amdgcn_sched_barrier(0);
    }

    // final h, c (fp32)
    if (l < 16) {
        const size_t HO = (size_t)SEQ * BATCH * HDIM;
        out[HO + (size_t)b * HDIM + u] = hval;
        out[HO + (size_t)BATCH * HDIM + (size_t)b * HDIM + u] = c_state;
    }
}

extern "C" void kernel_launch(void* const* d_in, const int* in_sizes, int n_in,
                              void* d_out, int out_size, void* d_ws, size_t ws_size,
                              hipStream_t stream) {
    const float* xin = (const float*)d_in[0];
    const float* Wih = (const float*)d_in[1];
    const float* Whh = (const float*)d_in[2];
    const float* bih = (const float*)d_in[3];
    const float* bhh = (const float*)d_in[4];
    float* out = (float*)d_out;

    lstm_mfma4<<<BATCH, 256, 0, stream>>>(xin, Wih, Whh, bih, bhh, out);
}

// Round 12
// 550.458 us; speedup vs baseline: 1.0364x; 1.0364x over previous
//
#include <hip/hip_runtime.h>
#include <hip/hip_bf16.h>

#define SEQ   2048
#define BATCH 256
#define HDIM  64
#define GDIM  256   // 4*H

typedef __attribute__((ext_vector_type(8))) short bf16x8;  // 8 bf16 = 4 VGPR
typedef __attribute__((ext_vector_type(4))) float f32x4;

static __device__ __forceinline__ unsigned short f2bf(float f) {
    return __builtin_bit_cast(unsigned short, __float2bfloat16(f));
}

// MFMA LSTM (r9 skeleton, champion 514us) + two register-only chain cuts:
// (1) exp2 scales (-log2e; -2log2e for gate g) folded into Whh/Wih/bias at
//     init -> MFMA output IS the exp2 argument (no post-MFMA mul).
// (2) bias + x@Wih folded into the first MFMA's C operand, built at the top
//     of the step while the ds_reads are in flight (no post-MFMA adds).
// One WG per batch element, 4 waves; wave w owns units [16w,16w+16).
// Per step: 4 parallel depth-2 mfma_16x16x32_bf16 chains; h fed back as bf16
// via LDS; saturating sigmoid/tanh forms; raw lgkmcnt(0)+s_barrier (global
// stores stay in flight). D layout (validated r8): col=lane&15, rows
// replicated -> lane reads acc[0].
__global__ __launch_bounds__(256, 1) void lstm_mfma5(
    const float* __restrict__ xin,   // [S,B,2]
    const float* __restrict__ Wih,   // [2,256]
    const float* __restrict__ Whh,   // [64,256]
    const float* __restrict__ bih,   // [256]
    const float* __restrict__ bhh,   // [256]
    float* __restrict__ out)         // fp32: hidden_seq [S,B,64] | h [B,64] | c [B,64]
{
    const int b   = blockIdx.x;
    const int tid = threadIdx.x;
    const int w   = tid >> 6;    // wave 0..3
    const int l   = tid & 63;    // lane
    const int lg  = l >> 4;      // k-group 0..3
    const int lc  = l & 15;      // tile column
    const int u   = 16 * w + lc; // hidden unit this lane handles

    __shared__ __align__(16) unsigned short v_hi[2][HDIM];  // h bf16, dbuf
    __shared__ float2 xf[SEQ];                              // staged x pairs (fp32)

    // ---- stage x for this batch column ----
    const float2* x2 = reinterpret_cast<const float2*>(xin);
    #pragma unroll
    for (int r = 0; r < SEQ / 256; ++r) {
        int s = r * 256 + tid;
        xf[s] = x2[(size_t)s * BATCH + b];
    }

    const float L2E = 1.44269504088896340736f;

    // ---- persistent weight fragments, pre-scaled so MFMA out = exp2 arg ----
    bf16x8 wf[4][2];
    float  wx0[4], wx1[4], bias[4];
    #pragma unroll
    for (int t = 0; t < 4; ++t) {
        const float scale = (t == 2) ? -2.0f * L2E : -L2E;
        const int g = 64 * t + 16 * w + lc;
        #pragma unroll
        for (int kc = 0; kc < 2; ++kc) {
            bf16x8 f;
            #pragma unroll
            for (int e = 0; e < 8; ++e) {
                int k = 32 * kc + 8 * lg + e;
                f[e] = (short)f2bf(scale * Whh[k * GDIM + g]);
            }
            wf[t][kc] = f;
        }
        wx0[t]  = scale * Wih[0 * GDIM + g];
        wx1[t]  = scale * Wih[1 * GDIM + g];
        bias[t] = scale * (bih[g] + bhh[g]);
    }

    if (tid < HDIM) { v_hi[0][tid] = 0; v_hi[1][tid] = 0; }
    float c_state = 0.0f, hval = 0.0f;
    __syncthreads();

    for (int s = 0; s < SEQ; ++s) {
        const int buf = s & 1;
        // A fragments: h vector, identical across the 16 replica rows
        bf16x8 ah0 = *reinterpret_cast<const bf16x8*>(&v_hi[buf][8 * lg]);       // k 0..31
        bf16x8 ah1 = *reinterpret_cast<const bf16x8*>(&v_hi[buf][32 + 8 * lg]);  // k 32..63

        // C operand = bias + x@Wih (scaled), built while ds_reads are in flight
        const float2 xv = xf[s];
        f32x4 c0[4];
        #pragma unroll
        for (int t = 0; t < 4; ++t) {
            const float xbt = __builtin_fmaf(wx0[t], xv.x,
                              __builtin_fmaf(wx1[t], xv.y, bias[t]));
            c0[t] = (f32x4){xbt, xbt, xbt, xbt};
        }

        // 4 parallel depth-2 MFMA chains; output IS the exp2 argument
        f32x4 acc[4];
        #pragma unroll
        for (int t = 0; t < 4; ++t)
            acc[t] = __builtin_amdgcn_mfma_f32_16x16x32_bf16(ah0, wf[t][0], c0[t], 0, 0, 0);
        #pragma unroll
        for (int t = 0; t < 4; ++t)
            acc[t] = __builtin_amdgcn_mfma_f32_16x16x32_bf16(ah1, wf[t][1], acc[t], 0, 0, 0);

        // activations (in-lane): i,f,o sigmoid; g tanh (saturating forms)
        const float iv = __builtin_amdgcn_rcpf(1.0f + __builtin_amdgcn_exp2f(acc[0][0]));
        const float fv = __builtin_amdgcn_rcpf(1.0f + __builtin_amdgcn_exp2f(acc[1][0]));
        const float gv = 2.0f * __builtin_amdgcn_rcpf(1.0f + __builtin_amdgcn_exp2f(acc[2][0])) - 1.0f;
        const float ov = __builtin_amdgcn_rcpf(1.0f + __builtin_amdgcn_exp2f(acc[3][0]));

        c_state = fv * c_state + iv * gv;
        const float tc = 2.0f * __builtin_amdgcn_rcpf(1.0f + __builtin_amdgcn_exp2f(-2.0f * L2E * c_state)) - 1.0f;
        hval = ov * tc;

        if (l < 16) {
            v_hi[buf ^ 1][u] = f2bf(hval);   // feed next step (bf16)
            out[(size_t)s * (BATCH * HDIM) + (size_t)b * HDIM + u] = hval;  // fire-and-forget
        }

        // LDS-only barrier: order h exchange WITHOUT draining global stores
        __builtin_amdgcn_sched_barrier(0);
        asm volatile("s_waitcnt lgkmcnt(0)\n\ts_barrier" ::: "memory");
        __builtin_amdgcn_sched_barrier(0);
    }

    // final h, c (fp32)
    if (l < 16) {
        const size_t HO = (size_t)SEQ * BATCH * HDIM;
        out[HO + (size_t)b * HDIM + u] = hval;
        out[HO + (size_t)BATCH * HDIM + (size_t)b * HDIM + u] = c_state;
    }
}

extern "C" void kernel_launch(void* const* d_in, const int* in_sizes, int n_in,
                              void* d_out, int out_size, void* d_ws, size_t ws_size,
                              hipStream_t stream) {
    const float* xin = (const float*)d_in[0];
    const float* Wih = (const float*)d_in[1];
    const float* Whh = (const float*)d_in[2];
    const float* bih = (const float*)d_in[3];
    const float* bhh = (const float*)d_in[4];
    float* out = (float*)d_out;

    lstm_mfma5<<<BATCH, 256, 0, stream>>>(xin, Wih, Whh, bih, bhh, out);
}

// Round 13
// 530.269 us; speedup vs baseline: 1.0758x; 1.0381x over previous
//
#include <hip/hip_runtime.h>
#include <hip/hip_bf16.h>

#define SEQ   2048
#define BATCH 256
#define HDIM  64
#define GDIM  256   // 4*H

typedef __attribute__((ext_vector_type(8))) short bf16x8;  // 8 bf16 = 4 VGPR
typedef __attribute__((ext_vector_type(4))) float f32x4;

static __device__ __forceinline__ unsigned short f2bf(float f) {
    return __builtin_bit_cast(unsigned short, __float2bfloat16(f));
}

// MFMA LSTM — r9 arithmetic (champion, 514us), scheduling unshackled:
// * no sched_barrier around the raw lgkmcnt(0)+s_barrier: the asm's "memory"
//   clobber orders all LDS/global ops; register-only work (next-step x-proj,
//   c bookkeeping, loop control) may now cross the barrier and fill the
//   barrier+ds_read latency window.
// * x carried in a register (prefetched mid-iteration), output pointer
//   advanced incrementally.
// One WG per batch element, 4 waves; wave w owns units [16w,16w+16).
// Per step: 4 parallel depth-2 mfma_16x16x32_bf16 chains (bias in C),
// xb added post-MFMA; h fed back as bf16 via LDS; saturating sigmoid/tanh.
// D layout (validated r8): col=lane&15, rows replicated -> lane reads acc[0].
__global__ __launch_bounds__(256, 1) void lstm_mfma6(
    const float* __restrict__ xin,   // [S,B,2]
    const float* __restrict__ Wih,   // [2,256]
    const float* __restrict__ Whh,   // [64,256]
    const float* __restrict__ bih,   // [256]
    const float* __restrict__ bhh,   // [256]
    float* __restrict__ out)         // fp32: hidden_seq [S,B,64] | h [B,64] | c [B,64]
{
    const int b   = blockIdx.x;
    const int tid = threadIdx.x;
    const int w   = tid >> 6;    // wave 0..3
    const int l   = tid & 63;    // lane
    const int lg  = l >> 4;      // k-group 0..3
    const int lc  = l & 15;      // tile column
    const int u   = 16 * w + lc; // hidden unit this lane handles

    __shared__ __align__(16) unsigned short v_hi[2][HDIM];  // h bf16, dbuf
    __shared__ float2 xf[SEQ];                              // staged x pairs (fp32)

    // ---- stage x for this batch column ----
    const float2* x2 = reinterpret_cast<const float2*>(xin);
    #pragma unroll
    for (int r = 0; r < SEQ / 256; ++r) {
        int s = r * 256 + tid;
        xf[s] = x2[(size_t)s * BATCH + b];
    }

    // ---- persistent weight fragments (B operand): gate g = 64t + 16w + lc,
    //      k = 32*kc + 8*lg + e ----
    bf16x8 wf[4][2];
    f32x4  biasv[4];
    float  wx0[4], wx1[4];
    #pragma unroll
    for (int t = 0; t < 4; ++t) {
        const int g = 64 * t + 16 * w + lc;
        #pragma unroll
        for (int kc = 0; kc < 2; ++kc) {
            bf16x8 f;
            #pragma unroll
            for (int e = 0; e < 8; ++e) {
                int k = 32 * kc + 8 * lg + e;
                f[e] = (short)f2bf(Whh[k * GDIM + g]);
            }
            wf[t][kc] = f;
        }
        wx0[t] = Wih[0 * GDIM + g];
        wx1[t] = Wih[1 * GDIM + g];
        const float bb = bih[g] + bhh[g];
        biasv[t] = (f32x4){bb, bb, bb, bb};
    }

    if (tid < HDIM) { v_hi[0][tid] = 0; v_hi[1][tid] = 0; }
    float c_state = 0.0f, hval = 0.0f;
    float* outp = out + (size_t)b * HDIM + u;   // hidden_seq[0][b][u]
    __syncthreads();

    const float L2E = 1.44269504088896340736f;
    float2 xv = xf[0];

    for (int s = 0; s < SEQ; ++s) {
        const int buf = s & 1;
        // A fragments: h vector, identical across the 16 replica rows
        bf16x8 ah0 = *reinterpret_cast<const bf16x8*>(&v_hi[buf][8 * lg]);       // k 0..31
        bf16x8 ah1 = *reinterpret_cast<const bf16x8*>(&v_hi[buf][32 + 8 * lg]);  // k 32..63

        // x contribution in fp32 on VALU (current step's xv carried in reg)
        float xb[4];
        #pragma unroll
        for (int t = 0; t < 4; ++t)
            xb[t] = wx0[t] * xv.x + wx1[t] * xv.y;

        // prefetch next step's x (free to float across the barrier)
        xv = xf[(s + 1) & (SEQ - 1)];

        // 4 parallel depth-2 MFMA chains (bias in C)
        f32x4 acc[4];
        #pragma unroll
        for (int t = 0; t < 4; ++t)
            acc[t] = __builtin_amdgcn_mfma_f32_16x16x32_bf16(ah0, wf[t][0], biasv[t], 0, 0, 0);
        #pragma unroll
        for (int t = 0; t < 4; ++t)
            acc[t] = __builtin_amdgcn_mfma_f32_16x16x32_bf16(ah1, wf[t][1], acc[t], 0, 0, 0);

        const float ip = acc[0][0] + xb[0];
        const float fp = acc[1][0] + xb[1];
        const float gp = acc[2][0] + xb[2];
        const float op = acc[3][0] + xb[3];

        // activations (in-lane): i,f,o sigmoid; g tanh (saturating forms)
        const float iv = __builtin_amdgcn_rcpf(1.0f + __builtin_amdgcn_exp2f(-L2E * ip));
        const float fv = __builtin_amdgcn_rcpf(1.0f + __builtin_amdgcn_exp2f(-L2E * fp));
        const float gv = 2.0f * __builtin_amdgcn_rcpf(1.0f + __builtin_amdgcn_exp2f(-2.0f * L2E * gp)) - 1.0f;
        const float ov = __builtin_amdgcn_rcpf(1.0f + __builtin_amdgcn_exp2f(-L2E * op));

        c_state = fv * c_state + iv * gv;
        const float tc = 2.0f * __builtin_amdgcn_rcpf(1.0f + __builtin_amdgcn_exp2f(-2.0f * L2E * c_state)) - 1.0f;
        hval = ov * tc;

        if (l < 16) {
            v_hi[buf ^ 1][u] = f2bf(hval);   // feed next step (bf16)
            *outp = hval;                     // fire-and-forget
        }
        outp += BATCH * HDIM;

        // LDS barrier: "memory" clobber orders ds ops; registers may cross
        asm volatile("s_waitcnt lgkmcnt(0)\n\ts_barrier" ::: "memory");
    }

    // final h, c (fp32)
    if (l < 16) {
        const size_t HO = (size_t)SEQ * BATCH * HDIM;
        out[HO + (size_t)b * HDIM + u] = hval;
        out[HO + (size_t)BATCH * HDIM + (size_t)b * HDIM + u] = c_state;
    }
}

extern "C" void kernel_launch(void* const* d_in, const int* in_sizes, int n_in,
                              void* d_out, int out_size, void* d_ws, size_t ws_size,
                              hipStream_t stream) {
    const float* xin = (const float*)d_in[0];
    const float* Wih = (const float*)d_in[1];
    const float* Whh = (const float*)d_in[2];
    const float* bih = (const float*)d_in[3];
    const float* bhh = (const float*)d_in[4];
    float* out = (float*)d_out;

    lstm_mfma6<<<BATCH, 256, 0, stream>>>(xin, Wih, Whh, bih, bhh, out);
}

// Round 14
// 525.266 us; speedup vs baseline: 1.0861x; 1.0095x over previous
//
#include <hip/hip_runtime.h>
#include <hip/hip_bf16.h>

#define SEQ   2048
#define BATCH 256
#define HDIM  64
#define GDIM  256   // 4*H

typedef __attribute__((ext_vector_type(8))) short bf16x8;  // 8 bf16 = 4 VGPR
typedef __attribute__((ext_vector_type(4))) float f32x4;

static __device__ __forceinline__ unsigned short f2bf(float f) {
    return __builtin_bit_cast(unsigned short, __float2bfloat16(f));
}

// MFMA LSTM — r9 skeleton (champion 514us), ONE change: MFMA issue order is
// t-major with critical gates first (g,i then f,o) instead of level-major.
// The c-chain head (gv,iv -> ivg -> c) starts its exp2/rcp while f and o's
// MFMAs still occupy the matrix pipe -> trans issue overlaps MFMA pipe time.
// Bit-identical arithmetic to r9 otherwise.
// One WG per batch element, 4 waves; wave w owns units [16w,16w+16).
// D layout (validated r8): col=lane&15, rows replicated -> lane reads acc[0].
// Barrier = sched_barrier-fenced raw lgkmcnt(0)+s_barrier (r9's exact form).
__global__ __launch_bounds__(256, 1) void lstm_mfma7(
    const float* __restrict__ xin,   // [S,B,2]
    const float* __restrict__ Wih,   // [2,256]
    const float* __restrict__ Whh,   // [64,256]
    const float* __restrict__ bih,   // [256]
    const float* __restrict__ bhh,   // [256]
    float* __restrict__ out)         // fp32: hidden_seq [S,B,64] | h [B,64] | c [B,64]
{
    const int b   = blockIdx.x;
    const int tid = threadIdx.x;
    const int w   = tid >> 6;    // wave 0..3
    const int l   = tid & 63;    // lane
    const int lg  = l >> 4;      // k-group 0..3
    const int lc  = l & 15;      // tile column
    const int u   = 16 * w + lc; // hidden unit this lane handles

    __shared__ __align__(16) unsigned short v_hi[2][HDIM];  // h bf16, dbuf
    __shared__ float2 xf[SEQ];                              // staged x pairs (fp32)

    // ---- stage x for this batch column ----
    const float2* x2 = reinterpret_cast<const float2*>(xin);
    #pragma unroll
    for (int r = 0; r < SEQ / 256; ++r) {
        int s = r * 256 + tid;
        xf[s] = x2[(size_t)s * BATCH + b];
    }

    // ---- persistent weight fragments (B operand): gate g = 64t + 16w + lc,
    //      k = 32*kc + 8*lg + e ----
    bf16x8 wf[4][2];
    f32x4  biasv[4];
    float  wx0[4], wx1[4];
    #pragma unroll
    for (int t = 0; t < 4; ++t) {
        const int g = 64 * t + 16 * w + lc;
        #pragma unroll
        for (int kc = 0; kc < 2; ++kc) {
            bf16x8 f;
            #pragma unroll
            for (int e = 0; e < 8; ++e) {
                int k = 32 * kc + 8 * lg + e;
                f[e] = (short)f2bf(Whh[k * GDIM + g]);
            }
            wf[t][kc] = f;
        }
        wx0[t] = Wih[0 * GDIM + g];
        wx1[t] = Wih[1 * GDIM + g];
        const float bb = bih[g] + bhh[g];
        biasv[t] = (f32x4){bb, bb, bb, bb};
    }

    if (tid < HDIM) { v_hi[0][tid] = 0; v_hi[1][tid] = 0; }
    float c_state = 0.0f, hval = 0.0f;
    __syncthreads();

    const float L2E = 1.44269504088896340736f;

    for (int s = 0; s < SEQ; ++s) {
        const int buf = s & 1;
        // A fragments: h vector, identical across the 16 replica rows
        bf16x8 ah0 = *reinterpret_cast<const bf16x8*>(&v_hi[buf][8 * lg]);       // k 0..31
        bf16x8 ah1 = *reinterpret_cast<const bf16x8*>(&v_hi[buf][32 + 8 * lg]);  // k 32..63

        // x contribution in fp32 on VALU (overlaps the ds_reads)
        const float2 xv = xf[s];
        float xb[4];
        #pragma unroll
        for (int t = 0; t < 4; ++t)
            xb[t] = wx0[t] * xv.x + wx1[t] * xv.y;

        // t-major MFMA issue, critical gates first: g, i (head of the c-chain),
        // then f (needed mid-chain), then o (needed last).
        f32x4 accg, acci, accf, acco;
        accg = __builtin_amdgcn_mfma_f32_16x16x32_bf16(ah0, wf[2][0], biasv[2], 0, 0, 0);
        accg = __builtin_amdgcn_mfma_f32_16x16x32_bf16(ah1, wf[2][1], accg,     0, 0, 0);
        acci = __builtin_amdgcn_mfma_f32_16x16x32_bf16(ah0, wf[0][0], biasv[0], 0, 0, 0);
        acci = __builtin_amdgcn_mfma_f32_16x16x32_bf16(ah1, wf[0][1], acci,     0, 0, 0);
        accf = __builtin_amdgcn_mfma_f32_16x16x32_bf16(ah0, wf[1][0], biasv[1], 0, 0, 0);
        accf = __builtin_amdgcn_mfma_f32_16x16x32_bf16(ah1, wf[1][1], accf,     0, 0, 0);
        acco = __builtin_amdgcn_mfma_f32_16x16x32_bf16(ah0, wf[3][0], biasv[3], 0, 0, 0);
        acco = __builtin_amdgcn_mfma_f32_16x16x32_bf16(ah1, wf[3][1], acco,     0, 0, 0);

        // activations in dependency-priority order (g,i first — c-chain head)
        const float gp = accg[0] + xb[2];
        const float gv = 2.0f * __builtin_amdgcn_rcpf(1.0f + __builtin_amdgcn_exp2f(-2.0f * L2E * gp)) - 1.0f;
        const float ip = acci[0] + xb[0];
        const float iv = __builtin_amdgcn_rcpf(1.0f + __builtin_amdgcn_exp2f(-L2E * ip));
        const float ivg = iv * gv;

        const float fp = accf[0] + xb[1];
        const float fv = __builtin_amdgcn_rcpf(1.0f + __builtin_amdgcn_exp2f(-L2E * fp));
        c_state = fv * c_state + ivg;

        const float tc = 2.0f * __builtin_amdgcn_rcpf(1.0f + __builtin_amdgcn_exp2f(-2.0f * L2E * c_state)) - 1.0f;
        const float op = acco[0] + xb[3];
        const float ov = __builtin_amdgcn_rcpf(1.0f + __builtin_amdgcn_exp2f(-L2E * op));
        hval = ov * tc;

        if (l < 16) {
            v_hi[buf ^ 1][u] = f2bf(hval);   // feed next step (bf16)
            out[(size_t)s * (BATCH * HDIM) + (size_t)b * HDIM + u] = hval;  // fire-and-forget
        }

        // LDS-only barrier (r9's exact fenced form)
        __builtin_amdgcn_sched_barrier(0);
        asm volatile("s_waitcnt lgkmcnt(0)\n\ts_barrier" ::: "memory");
        __builtin_amdgcn_sched_barrier(0);
    }

    // final h, c (fp32)
    if (l < 16) {
        const size_t HO = (size_t)SEQ * BATCH * HDIM;
        out[HO + (size_t)b * HDIM + u] = hval;
        out[HO + (size_t)BATCH * HDIM + (size_t)b * HDIM + u] = c_state;
    }
}

extern "C" void kernel_launch(void* const* d_in, const int* in_sizes, int n_in,
                              void* d_out, int out_size, void* d_ws, size_t ws_size,
                              hipStream_t stream) {
    const float* xin = (const float*)d_in[0];
    const float* Wih = (const float*)d_in[1];
    const float* Whh = (const float*)d_in[2];
    const float* bih = (const float*)d_in[3];
    const float* bhh = (const float*)d_in[4];
    float* out = (float*)d_out;

    lstm_mfma7<<<BATCH, 256, 0, stream>>>(xin, Wih, Whh, bih, bhh, out);
}